// Round 1
// baseline (26.901 us; speedup 1.0000x reference)
//
#include <hip/hip_runtime.h>
#include <hip/hip_bf16.h>

// GMM 2D activation: out = x * gmm2d(x)
// x: (2, 4096, 2048) fp32, viewed as pairs (D/2, 2).
// Per pair p, component k: log_g = -0.5 * diff^T IVC_k diff
// out[o] = x[o] * sum_k exp(log_g[k]) * exp(log_weights[k][o])
// (max-subtraction in reference cancels exactly; IVC is PSD so log_g <= 0
//  and direct exp-sum is numerically safe.)

__global__ __launch_bounds__(256) void gmm2d_act_kernel(
    const float4* __restrict__ x,
    const float*  __restrict__ means,   // (K,2)
    const float*  __restrict__ ivc,     // (K,2,2)
    const float*  __restrict__ lw,      // (K,2)
    float4* __restrict__ out,
    int n4)
{
    // Per-thread broadcast load of the 28 GMM parameters into registers.
    float m0[4], m1[4], Aq[4], Bq[4], Cq[4], W0[4], W1[4];
#pragma unroll
    for (int k = 0; k < 4; ++k) {
        m0[k] = means[2*k + 0];
        m1[k] = means[2*k + 1];
        Aq[k] = -0.5f *  ivc[4*k + 0];
        Bq[k] = -0.5f * (ivc[4*k + 1] + ivc[4*k + 2]);
        Cq[k] = -0.5f *  ivc[4*k + 3];
        W0[k] = expf(lw[2*k + 0]);   // precise expf once per thread
        W1[k] = expf(lw[2*k + 1]);
    }

    const int stride = gridDim.x * blockDim.x;
    for (int i = blockIdx.x * blockDim.x + threadIdx.x; i < n4; i += stride) {
        float4 v = x[i];
        float r0, r1, r2, r3;
        // pair 0: (v.x, v.y)
        {
            float s0 = 0.f, s1 = 0.f;
#pragma unroll
            for (int k = 0; k < 4; ++k) {
                float d0 = v.x - m0[k];
                float d1 = v.y - m1[k];
                float q  = Aq[k]*d0*d0 + Bq[k]*d0*d1 + Cq[k]*d1*d1;
                float e  = __expf(q);
                s0 = fmaf(e, W0[k], s0);
                s1 = fmaf(e, W1[k], s1);
            }
            r0 = v.x * s0;
            r1 = v.y * s1;
        }
        // pair 1: (v.z, v.w)
        {
            float s0 = 0.f, s1 = 0.f;
#pragma unroll
            for (int k = 0; k < 4; ++k) {
                float d0 = v.z - m0[k];
                float d1 = v.w - m1[k];
                float q  = Aq[k]*d0*d0 + Bq[k]*d0*d1 + Cq[k]*d1*d1;
                float e  = __expf(q);
                s0 = fmaf(e, W0[k], s0);
                s1 = fmaf(e, W1[k], s1);
            }
            r2 = v.z * s0;
            r3 = v.w * s1;
        }
        out[i] = make_float4(r0, r1, r2, r3);
    }
}

extern "C" void kernel_launch(void* const* d_in, const int* in_sizes, int n_in,
                              void* d_out, int out_size, void* d_ws, size_t ws_size,
                              hipStream_t stream) {
    const float4* x   = (const float4*)d_in[0];   // (2,4096,2048) fp32
    const float* means = (const float*)d_in[1];    // (1,1,4,2)
    const float* ivc   = (const float*)d_in[2];    // (4,2,2)
    const float* lw    = (const float*)d_in[3];    // (1,1,1,4,2)
    float4* out = (float4*)d_out;

    const int n4 = out_size / 4;                   // 4,194,304 float4s
    const int block = 256;
    const int grid = 2048;                         // 8 blocks/CU, grid-stride x8

    gmm2d_act_kernel<<<grid, block, 0, stream>>>(x, means, ivc, lw, out, n4);
}

// Round 3
// 26.565 us; speedup vs baseline: 1.0126x; 1.0126x over previous
//
#include <hip/hip_runtime.h>
#include <hip/hip_bf16.h>

// GMM 2D activation: out = x * gmm2d(x)
// x: (2, 4096, 2048) fp32, viewed as pairs (D/2, 2).
// out[o] = x[o] * sum_k exp(-0.5 diff^T IVC_k diff) * exp(log_weights[k][o])
// Max-subtraction in the reference cancels exactly; IVC is PSD so the
// exponent is <= 0 and direct exp-sum is numerically safe.
// exp(q) computed as exp2(q * log2e) with log2e folded into the
// quadratic coefficients -> single native v_exp_f32 per component.

#define LOG2E 1.4426950408889634f

typedef float f32x4 __attribute__((ext_vector_type(4)));

template <int ITERS>
__global__ __launch_bounds__(256) void gmm2d_act_kernel(
    const f32x4* __restrict__ x,
    const float* __restrict__ means,   // (K,2)
    const float* __restrict__ ivc,     // (K,2,2)
    const float* __restrict__ lw,      // (K,2)
    f32x4* __restrict__ out,
    int n4)
{
    // Per-thread broadcast load of the 28 GMM parameters into registers.
    float m0[4], m1[4], Aq[4], Bq[4], Cq[4], W0[4], W1[4];
#pragma unroll
    for (int k = 0; k < 4; ++k) {
        m0[k] = means[2*k + 0];
        m1[k] = means[2*k + 1];
        Aq[k] = -0.5f * LOG2E *  ivc[4*k + 0];
        Bq[k] = -0.5f * LOG2E * (ivc[4*k + 1] + ivc[4*k + 2]);
        Cq[k] = -0.5f * LOG2E *  ivc[4*k + 3];
        W0[k] = expf(lw[2*k + 0]);   // precise expf, once per thread
        W1[k] = expf(lw[2*k + 1]);
    }

    const int stride = gridDim.x * blockDim.x;
    const int tid = blockIdx.x * blockDim.x + threadIdx.x;

    if (ITERS * stride == n4 || tid + (ITERS - 1) * stride < n4) {
        // Fast path: issue all ITERS loads up front for max MLP.
        f32x4 v[ITERS];
#pragma unroll
        for (int it = 0; it < ITERS; ++it)
            v[it] = x[tid + it * stride];

#pragma unroll
        for (int it = 0; it < ITERS; ++it) {
            f32x4 r;
#pragma unroll
            for (int p = 0; p < 2; ++p) {
                float x0 = v[it][2*p + 0];
                float x1 = v[it][2*p + 1];
                float s0 = 0.f, s1 = 0.f;
#pragma unroll
                for (int k = 0; k < 4; ++k) {
                    float d0 = x0 - m0[k];
                    float d1 = x1 - m1[k];
                    // q = d0*(Aq*d0 + Bq*d1) + Cq*d1*d1  (pre-scaled by log2e)
                    float t  = fmaf(Bq[k], d1, Aq[k] * d0);
                    float q  = fmaf(Cq[k] * d1, d1, d0 * t);
                    float e  = __builtin_amdgcn_exp2f(q);
                    s0 = fmaf(e, W0[k], s0);
                    s1 = fmaf(e, W1[k], s1);
                }
                r[2*p + 0] = x0 * s0;
                r[2*p + 1] = x1 * s1;
            }
            // Streaming store: output is never re-read by this kernel.
            __builtin_nontemporal_store(r, &out[tid + it * stride]);
        }
    } else {
        // Tail path (unused for the 2^22 problem size; kept for safety).
        for (int i = tid; i < n4; i += stride) {
            f32x4 v = x[i];
            f32x4 r;
#pragma unroll
            for (int p = 0; p < 2; ++p) {
                float x0 = v[2*p + 0];
                float x1 = v[2*p + 1];
                float s0 = 0.f, s1 = 0.f;
#pragma unroll
                for (int k = 0; k < 4; ++k) {
                    float d0 = x0 - m0[k];
                    float d1 = x1 - m1[k];
                    float t  = fmaf(Bq[k], d1, Aq[k] * d0);
                    float q  = fmaf(Cq[k] * d1, d1, d0 * t);
                    float e  = __builtin_amdgcn_exp2f(q);
                    s0 = fmaf(e, W0[k], s0);
                    s1 = fmaf(e, W1[k], s1);
                }
                r[2*p + 0] = x0 * s0;
                r[2*p + 1] = x1 * s1;
            }
            __builtin_nontemporal_store(r, &out[i]);
        }
    }
}

extern "C" void kernel_launch(void* const* d_in, const int* in_sizes, int n_in,
                              void* d_out, int out_size, void* d_ws, size_t ws_size,
                              hipStream_t stream) {
    const f32x4* x     = (const f32x4*)d_in[0];   // (2,4096,2048) fp32
    const float* means = (const float*)d_in[1];    // (1,1,4,2)
    const float* ivc   = (const float*)d_in[2];    // (4,2,2)
    const float* lw    = (const float*)d_in[3];    // (1,1,1,4,2)
    f32x4* out = (f32x4*)d_out;

    const int n4 = out_size / 4;                   // 4,194,304 float4s (2^22)
    const int block = 256;

    if (n4 % (4096 * block * 4) == 0) {
        // 1,048,576 threads x 4 float4 each, fully unrolled, no bounds checks
        gmm2d_act_kernel<4><<<4096, block, 0, stream>>>(x, means, ivc, lw, out, n4);
    } else {
        gmm2d_act_kernel<1><<<(n4 + block - 1) / block, block, 0, stream>>>(x, means, ivc, lw, out, n4);
    }
}